// Round 7
// baseline (438.766 us; speedup 1.0000x reference)
//
#include <hip/hip_runtime.h>
#include <hip/hip_bf16.h>

// Problem constants
#define H_    16
#define NOPE_ 128
#define ROPE_ 64
#define VDIM_ 128
#define LORA_ 512
#define DM_   2048
#define T_    256
#define S_    32768
#define K_    2048

static constexpr float SCALE_ = 0.072168783648703220563643597562744f; // 1/sqrt(192)
static constexpr float LOG2E_ = 1.4426950408889634f;

typedef __attribute__((ext_vector_type(8))) short short8;   // 8 bf16 in 4 VGPRs
typedef __attribute__((ext_vector_type(4))) float f32x4;    // MFMA accumulator

__device__ __forceinline__ ushort f2bf(float f) {
    unsigned u = __float_as_uint(f);
    unsigned r = (u + 0x7FFFu + ((u >> 16) & 1u)) >> 16;    // RNE
    return (ushort)r;
}
__device__ __forceinline__ float bf2f(ushort u) {
    return __uint_as_float((unsigned)u << 16);
}

// async global->LDS 16B: per-lane global addr, wave-uniform LDS base,
// HW writes lane i at base + i*16  [guide §5 / m97]
__device__ __forceinline__ void gld_lds16(const void* g, void* l) {
    __builtin_amdgcn_global_load_lds(
        (const __attribute__((address_space(1))) unsigned int*)g,
        (__attribute__((address_space(3))) unsigned int*)l, 16, 0, 0);
}

// ---------------------------------------------------------------------------
// bf16 MFMA GEMM with register double-buffer prefetch.
// C[M,N] = A[M,K] @ B[K,N] (B_NT: B is [N][K] n-major).
// BM=BN=64, BK=64, 256 thr (4 waves, each 32x32 quadrant, 2x2 MFMA tiles).
// Layouts (HW-verified): A[m=l&15][k=(l>>4)*8+j]; B[k=(l>>4)*8+j][n=l&15];
// C/D[row=(l>>4)*4+reg][col=l&15].  M%64==0, N%64==0, K%64==0.
// ---------------------------------------------------------------------------
template<bool A_BF16, bool B_NT, bool C_BF16>
__global__ __launch_bounds__(256) void gemm_mfma(
    const void* __restrict__ Av, const float* __restrict__ B, void* __restrict__ Cv,
    int M, int N, int Kd, int lda, int ldb, int ldc,
    long batchA, long batchB, long batchC)
{
    __shared__ ushort As[64 * 72];
    __shared__ ushort Bs[64 * 72];

    const int tid = threadIdx.x;
    const int w  = tid >> 6;
    const int l  = tid & 63;
    const int lm = l & 15;
    const int kq = l >> 4;
    const int bm = blockIdx.y * 64;
    const int bn = blockIdx.x * 64;
    const int m0 = (w >> 1) * 32;
    const int n0 = (w & 1) * 32;

    const float*  Af = A_BF16 ? nullptr : ((const float*)Av)  + (long)blockIdx.z * batchA;
    const ushort* Ah = A_BF16 ? ((const ushort*)Av) + (long)blockIdx.z * batchA : nullptr;
    B += (long)blockIdx.z * batchB;

    // prefetch registers
    uint4  pa16[2];
    float4 pa32[4];
    float4 pb[4];

    const int am = tid >> 2,  ako = (tid & 3) * 16;          // A bf16 stage
    const int amr = tid >> 4, akk = (tid & 15) * 4;          // A fp32 stage
    const int bnr = tid >> 4, bkk = (tid & 15) * 4;          // B NT stage
    const int bk = tid >> 2,  bnq = (tid & 3) * 16;          // B NN stage

    auto loadA = [&](int k0) {
        if constexpr (A_BF16) {
            const ushort* s = Ah + (long)(bm + am) * lda + k0 + ako;
            pa16[0] = *(const uint4*)s;
            pa16[1] = *(const uint4*)(s + 8);
        } else {
            #pragma unroll
            for (int p = 0; p < 4; ++p)
                pa32[p] = *(const float4*)(Af + (long)(bm + amr + p * 16) * lda + k0 + akk);
        }
    };
    auto loadB = [&](int k0) {
        if constexpr (B_NT) {
            #pragma unroll
            for (int p = 0; p < 4; ++p)
                pb[p] = *(const float4*)(B + (long)(bn + bnr + p * 16) * ldb + k0 + bkk);
        } else {
            #pragma unroll
            for (int p = 0; p < 4; ++p)
                pb[p] = *(const float4*)(B + (long)(k0 + bk) * ldb + bn + bnq + p * 4);
        }
    };
    auto storeAB = [&]() {
        if constexpr (A_BF16) {
            *(uint4*)(As + am * 72 + ako)     = pa16[0];
            *(uint4*)(As + am * 72 + ako + 8) = pa16[1];
        } else {
            #pragma unroll
            for (int p = 0; p < 4; ++p) {
                ushort4 u;
                u.x = f2bf(pa32[p].x); u.y = f2bf(pa32[p].y);
                u.z = f2bf(pa32[p].z); u.w = f2bf(pa32[p].w);
                *(ushort4*)(As + (amr + p * 16) * 72 + akk) = u;
            }
        }
        if constexpr (B_NT) {
            #pragma unroll
            for (int p = 0; p < 4; ++p) {
                ushort4 u;
                u.x = f2bf(pb[p].x); u.y = f2bf(pb[p].y);
                u.z = f2bf(pb[p].z); u.w = f2bf(pb[p].w);
                *(ushort4*)(Bs + (bnr + p * 16) * 72 + bkk) = u;
            }
        } else {
            #pragma unroll
            for (int p = 0; p < 4; ++p) {
                ushort4 u;
                u.x = f2bf(pb[p].x); u.y = f2bf(pb[p].y);
                u.z = f2bf(pb[p].z); u.w = f2bf(pb[p].w);
                *(ushort4*)(Bs + bk * 68 + bnq + p * 4) = u;
            }
        }
    };

    f32x4 acc[2][2];
    #pragma unroll
    for (int i = 0; i < 2; ++i)
        #pragma unroll
        for (int j = 0; j < 2; ++j) acc[i][j] = (f32x4){0.f, 0.f, 0.f, 0.f};

    loadA(0);
    loadB(0);

    for (int k0 = 0; k0 < Kd; k0 += 64) {
        __syncthreads();          // previous tile's LDS consumers done
        storeAB();
        __syncthreads();
        if (k0 + 64 < Kd) {       // prefetch next tile while computing this one
            loadA(k0 + 64);
            loadB(k0 + 64);
        }
        #pragma unroll
        for (int ks = 0; ks < 2; ++ks) {
            short8 a[2], b[2];
            #pragma unroll
            for (int mt = 0; mt < 2; ++mt)
                a[mt] = *(const short8*)(As + (m0 + mt * 16 + lm) * 72 + ks * 32 + kq * 8);
            if constexpr (B_NT) {
                #pragma unroll
                for (int nt = 0; nt < 2; ++nt)
                    b[nt] = *(const short8*)(Bs + (n0 + nt * 16 + lm) * 72 + ks * 32 + kq * 8);
            } else {
                #pragma unroll
                for (int nt = 0; nt < 2; ++nt)
                    #pragma unroll
                    for (int j = 0; j < 8; ++j)
                        b[nt][j] = (short)Bs[(ks * 32 + kq * 8 + j) * 68 + n0 + nt * 16 + lm];
            }
            #pragma unroll
            for (int mt = 0; mt < 2; ++mt)
                #pragma unroll
                for (int nt = 0; nt < 2; ++nt)
                    acc[mt][nt] = __builtin_amdgcn_mfma_f32_16x16x32_bf16(
                        a[mt], b[nt], acc[mt][nt], 0, 0, 0);
        }
    }
    #pragma unroll
    for (int mt = 0; mt < 2; ++mt)
        #pragma unroll
        for (int nt = 0; nt < 2; ++nt)
            #pragma unroll
            for (int r = 0; r < 4; ++r) {
                long row = bm + m0 + mt * 16 + kq * 4 + r;
                long col = bn + n0 + nt * 16 + lm;
                if constexpr (C_BF16)
                    ((ushort*)Cv)[(long)blockIdx.z * batchC + row * ldc + col] =
                        f2bf(acc[mt][nt][r]);
                else
                    ((float*)Cv)[(long)blockIdx.z * batchC + row * ldc + col] =
                        acc[mt][nt][r];
            }
}

// ---------------------------------------------------------------------------
// qb[:, :, 512:576] = bf16(rope(q_pe)) from fp32 qfull. fp64 angles.
// ---------------------------------------------------------------------------
__global__ __launch_bounds__(256) void pack_qrope(
    const float* __restrict__ qfull, const int* __restrict__ pos_q,
    ushort* __restrict__ qb)
{
    int id = blockIdx.x * 256 + threadIdx.x;     // T*H*32 = 131072
    int i = id & 31;
    int h = (id >> 5) & 15;
    int t = id >> 9;
    double inv = exp2(-(double)i * 0.41524101186092026);  // 10000^(-i/32)
    double f = (double)pos_q[t] * inv;
    double fr = f - floor(f * 0.15915494309189535) * 6.283185307179586;
    float sf, cf;
    sincosf((float)fr, &sf, &cf);
    float x1 = qfull[t * 3072 + h * 192 + 128 + i];
    float x2 = qfull[t * 3072 + h * 192 + 160 + i];
    ushort* q = qb + (long)(t * 16 + h) * 576;
    q[512 + i] = f2bf(x1 * cf - x2 * sf);
    q[544 + i] = f2bf(x2 * cf + x1 * sf);
}

// ---------------------------------------------------------------------------
// kvb[s][0:512] = bf16(kv_c[s])   (pure copy/cast, no divergence)
// ---------------------------------------------------------------------------
__global__ __launch_bounds__(256) void prep_kv_copy(
    const float* __restrict__ kvc, ushort* __restrict__ kvb)
{
    int id = blockIdx.x * 256 + threadIdx.x;   // 32768*64 = 2,097,152
    int s = id >> 6;
    int d = (id & 63) * 8;
    const float* src = kvc + (long)s * 512 + d;
    float4 v0 = *(const float4*)src;
    float4 v1 = *(const float4*)(src + 4);
    ushort4 a, b;
    a.x = f2bf(v0.x); a.y = f2bf(v0.y); a.z = f2bf(v0.z); a.w = f2bf(v0.w);
    b.x = f2bf(v1.x); b.y = f2bf(v1.y); b.z = f2bf(v1.z); b.w = f2bf(v1.w);
    ushort* dst = kvb + (long)s * 576 + d;
    *(ushort4*)dst = a;
    *(ushort4*)(dst + 4) = b;
}

// ---------------------------------------------------------------------------
// kvb[s][512:576] = bf16(rope(k_pe[s], s))   (rope-only, all lanes uniform)
// ---------------------------------------------------------------------------
__global__ __launch_bounds__(256) void prep_kv_rope(
    const float* __restrict__ kpe, ushort* __restrict__ kvb)
{
    int id = blockIdx.x * 256 + threadIdx.x;   // 32768*32 = 1,048,576
    int i = id & 31;
    int s = id >> 5;
    double inv = exp2(-(double)i * 0.41524101186092026);
    double f = (double)s * inv;
    double fr = f - floor(f * 0.15915494309189535) * 6.283185307179586;
    float sf, cf;
    sincosf((float)fr, &sf, &cf);
    float x1 = kpe[(long)s * 64 + i];
    float x2 = kpe[(long)s * 64 + 32 + i];
    ushort* dst = kvb + (long)s * 576 + 512;
    dst[i]      = f2bf(x1 * cf - x2 * sf);
    dst[32 + i] = f2bf(x2 * cf + x1 * sf);
}

// ---------------------------------------------------------------------------
// Fused flash-MLA attention, split-K=2 (512 blocks, 2/CU, LDS 76.5 KB).
// kb tile: 64 keys x 72 16B-chunks, XOR-swizzled: chunk c of key r lives at
// slot c ^ g(r), g(r) = (r&7) ^ (((r>>3)&3)<<1).  This makes QK^T b128 reads
// AND PV scalar u16 column reads exactly 2-way (= free, m136).
// Staging via global_load_lds (per-lane gather addr, lane-contiguous LDS).
// ---------------------------------------------------------------------------
__global__ __launch_bounds__(256, 2) void mla_fused_split(
    const ushort* __restrict__ qb, const ushort* __restrict__ kvb,
    const int* __restrict__ topk,
    ushort* __restrict__ Opart, float* __restrict__ ml)
{
    __shared__ ushort kb[64 * 576];     // 73,728 B
    __shared__ ushort Pl[16 * 72];      // P in [h][key]
    __shared__ float wred[2][4][16];    // [max|sum][wave][row]

    const int t = blockIdx.x;
    const int sp = blockIdx.y;          // split 0/1
    const int tid = threadIdx.x;
    const int w = tid >> 6;
    const int l = tid & 63;
    const int lm = l & 15;
    const int kq = l >> 4;

    // ---- preload Q A-fragments (18 k-steps of 32) ----
    short8 qa[18];
    {
        const ushort* qrow = qb + (long)(t * 16 + lm) * 576 + kq * 8;
        #pragma unroll
        for (int ks = 0; ks < 18; ++ks)
            qa[ks] = *(const short8*)(qrow + ks * 32);
    }

    // ---- per-lane gather mapping: 18 chunk-loads/lane/tile ----
    // L = (w*18+i)*64 + l ; key = L/72 ; slot = L%72 ; source chunk = slot^g(key)
    int pk[18];     // key | (src_byte_off << 8)
    #pragma unroll
    for (int i = 0; i < 18; ++i) {
        int L = (w * 18 + i) * 64 + l;
        int key = L / 72;
        int s = L - key * 72;
        int g = (key & 7) ^ (((key >> 3) & 3) << 1);
        pk[i] = key | (((s ^ g) * 16) << 8);
    }

    const int* tkp = topk + (long)t * 2048 + sp * 1024;

    f32x4 O[8];
    #pragma unroll
    for (int vt = 0; vt < 8; ++vt) O[vt] = (f32x4){0.f, 0.f, 0.f, 0.f};
    float m_r[4] = {-1e30f, -1e30f, -1e30f, -1e30f};
    float l_r[4] = {0.f, 0.f, 0.f, 0.f};

    // QK^T-side constants
    const int keyq = w * 16 + lm;
    const int gq = (keyq & 7) ^ (((keyq >> 3) & 3) << 1);

    int idxv[18];
    #pragma unroll
    for (int i = 0; i < 18; ++i) idxv[i] = tkp[pk[i] & 255];

    for (int kt = 0; kt < 1024; kt += 64) {
        __syncthreads();   // previous tile's LDS reads done
        // ---- issue async gathers (16B per lane per issue) ----
        #pragma unroll
        for (int i = 0; i < 18; ++i) {
            const char* src = (const char*)kvb + (long)idxv[i] * 1152 + (pk[i] >> 8);
            gld_lds16(src, (char*)kb + (((w * 18 + i)) << 10));
        }
        // prefetch next tile's indices while gathers fly
        if (kt + 64 < 1024) {
            #pragma unroll
            for (int i = 0; i < 18; ++i) idxv[i] = tkp[kt + 64 + (pk[i] & 255)];
        }
        __syncthreads();   // drains vmcnt -> kb ready

        // ---- S = Q . K^T for this wave's 16 keys ----
        f32x4 S = (f32x4){0.f, 0.f, 0.f, 0.f};
        {
            const ushort* krow = kb + keyq * 576;
            #pragma unroll
            for (int ks = 0; ks < 18; ++ks) {
                int c = ks * 4 + kq;
                short8 bf = *(const short8*)(krow + ((c ^ gq) << 3));
                S = __builtin_amdgcn_mfma_f32_16x16x32_bf16(qa[ks], bf, S, 0, 0, 0);
            }
        }
        const int n0 = w * 16;
        float s4[4], mx[4], p[4];
        #pragma unroll
        for (int r = 0; r < 4; ++r) { s4[r] = S[r] * SCALE_; mx[r] = s4[r]; }
        #pragma unroll
        for (int off = 1; off < 16; off <<= 1)
            #pragma unroll
            for (int r = 0; r < 4; ++r)
                mx[r] = fmaxf(mx[r], __shfl_xor(mx[r], off, 64));
        if (lm == 0)
            #pragma unroll
            for (int r = 0; r < 4; ++r) wred[0][w][4 * kq + r] = mx[r];
        __syncthreads();

        float al[4], rs[4];
        #pragma unroll
        for (int r = 0; r < 4; ++r) {
            float tm = fmaxf(fmaxf(wred[0][0][4 * kq + r], wred[0][1][4 * kq + r]),
                             fmaxf(wred[0][2][4 * kq + r], wred[0][3][4 * kq + r]));
            float mn = fmaxf(m_r[r], tm);
            al[r] = exp2f((m_r[r] - mn) * LOG2E_);
            p[r] = exp2f((s4[r] - mn) * LOG2E_);
            m_r[r] = mn;
            rs[r] = p[r];
        }
        #pragma unroll
        for (int off = 1; off < 16; off <<= 1)
            #pragma unroll
            for (int r = 0; r < 4; ++r)
                rs[r] += __shfl_xor(rs[r], off, 64);
        if (lm == 0)
            #pragma unroll
            for (int r = 0; r < 4; ++r) wred[1][w][4 * kq + r] = rs[r];
        #pragma unroll
        for (int r = 0; r < 4; ++r)
            Pl[(4 * kq + r) * 72 + n0 + lm] = f2bf(p[r]);
        #pragma unroll
        for (int vt = 0; vt < 8; ++vt)
            #pragma unroll
            for (int r = 0; r < 4; ++r)
                O[vt][r] *= al[r];
        __syncthreads();   // Pl + wred[1] visible

        #pragma unroll
        for (int r = 0; r < 4; ++r) {
            float ts = wred[1][0][4 * kq + r] + wred[1][1][4 * kq + r] +
                       wred[1][2][4 * kq + r] + wred[1][3][4 * kq + r];
            l_r[r] = l_r[r] * al[r] + ts;
        }

        // ---- O += P . V (wave's 128-wide v range) ----
        short8 pa[2];
        #pragma unroll
        for (int ks = 0; ks < 2; ++ks)
            pa[ks] = *(const short8*)(Pl + lm * 72 + ks * 32 + kq * 8);
        const int v0 = w * 128;
        #pragma unroll
        for (int vt = 0; vt < 8; ++vt) {
            const int col = v0 + vt * 16 + lm;
            const int chi = col >> 3, clo = col & 7;
            #pragma unroll
            for (int ks = 0; ks < 2; ++ks) {
                short8 bv;
                #pragma unroll
                for (int j = 0; j < 8; ++j) {
                    int row = ks * 32 + kq * 8 + j;
                    int slot = chi ^ j ^ (kq << 1);   // g(row) = j ^ (kq<<1)
                    bv[j] = (short)kb[row * 576 + (slot << 3) + clo];
                }
                O[vt] = __builtin_amdgcn_mfma_f32_16x16x32_bf16(pa[ks], bv, O[vt], 0, 0, 0);
            }
        }
    }

    // ---- epilogue: store unnormalized partial O (bf16) + (m,l) ----
    const long rbase = ((long)sp * 256 + t) * 16;
    #pragma unroll
    for (int vt = 0; vt < 8; ++vt)
        #pragma unroll
        for (int r = 0; r < 4; ++r)
            Opart[(rbase + 4 * kq + r) * 512 + w * 128 + vt * 16 + lm] = f2bf(O[vt][r]);
    if (w == 0 && lm == 0) {
        #pragma unroll
        for (int r = 0; r < 4; ++r) {
            ml[(rbase + 4 * kq + r) * 2 + 0] = m_r[r];
            ml[(rbase + 4 * kq + r) * 2 + 1] = l_r[r];
        }
    }
}

// ---------------------------------------------------------------------------
// Merge the 2 split-K partials -> olat bf16.
// ---------------------------------------------------------------------------
__global__ __launch_bounds__(256) void combine_kernel(
    const ushort* __restrict__ Opart, const float* __restrict__ ml,
    ushort* __restrict__ olat)
{
    const int t = blockIdx.x;
    const int h = threadIdx.x >> 4;
    const int v0 = (threadIdx.x & 15) * 32;
    const long r0 = (long)t * 16 + h;
    const long r1 = (long)(256 + t) * 16 + h;
    float m0 = ml[r0 * 2], l0 = ml[r0 * 2 + 1];
    float m1 = ml[r1 * 2], l1 = ml[r1 * 2 + 1];
    float M = fmaxf(m0, m1);
    float w0 = exp2f((m0 - M) * LOG2E_);
    float w1 = exp2f((m1 - M) * LOG2E_);
    float inv = 1.0f / (w0 * l0 + w1 * l1);
    const ushort* p0 = Opart + r0 * 512 + v0;
    const ushort* p1 = Opart + r1 * 512 + v0;
    ushort* po = olat + r0 * 512 + v0;
    #pragma unroll
    for (int i = 0; i < 32; i += 4) {
        ushort4 a = *(const ushort4*)(p0 + i);
        ushort4 b = *(const ushort4*)(p1 + i);
        ushort4 o;
        o.x = f2bf((w0 * bf2f(a.x) + w1 * bf2f(b.x)) * inv);
        o.y = f2bf((w0 * bf2f(a.y) + w1 * bf2f(b.y)) * inv);
        o.z = f2bf((w0 * bf2f(a.z) + w1 * bf2f(b.z)) * inv);
        o.w = f2bf((w0 * bf2f(a.w) + w1 * bf2f(b.w)) * inv);
        *(ushort4*)(po + i) = o;
    }
}

// ---------------------------------------------------------------------------
// Launch. ws footprint exactly 54,001,664 B (proven safe in R5/R6).
//   qb    [0,          4,718,592)
//   qfull [4,718,592,  7,864,320)  (dead after GEMM2+pack_qrope)
//   Opart [4,718,592, 13,107,200)  overlay
//   ov_b  [13,107,200, 14,155,776)
//   ml    [14,155,776, 14,221,312)
//   kvb   [16,252,928, 54,001,664)
//   olat = overlay of qb (qb dead after attention)
// ---------------------------------------------------------------------------
extern "C" void kernel_launch(void* const* d_in, const int* in_sizes, int n_in,
                              void* d_out, int out_size, void* d_ws, size_t ws_size,
                              hipStream_t stream)
{
    const float* x    = (const float*)d_in[0];
    const float* Wq   = (const float*)d_in[1];
    const float* W_UK = (const float*)d_in[2];
    const float* W_UV = (const float*)d_in[3];
    const float* Wo   = (const float*)d_in[4];
    const float* kv_c = (const float*)d_in[5];
    const float* k_pe = (const float*)d_in[6];
    const int* topk   = (const int*)d_in[7];
    const int* pos_q  = (const int*)d_in[8];
    float* out        = (float*)d_out;

    char* wsb = (char*)d_ws;
    ushort* qb    = (ushort*)wsb;
    float*  qfull = (float*)(wsb + 4718592);
    ushort* Opart = (ushort*)(wsb + 4718592);          // overlay of qfull
    ushort* ov_b  = (ushort*)(wsb + 13107200);
    float*  ml    = (float*)(wsb + 14155776);
    ushort* olat  = qb;                                // overlay (qb dead)
    ushort* kvb   = (ushort*)(wsb + 16252928);
    if (ws_size < (size_t)54001664) return;            // fail loud, don't fault

    // 0) prep bf16 kv table (copy + rope, divergence-free)
    prep_kv_copy<<<8192, 256, 0, stream>>>(kv_c, kvb);
    prep_kv_rope<<<4096, 256, 0, stream>>>(k_pe, kvb);

    // 1) qfull = x @ Wq   (256 x 3072 x 2048), fp32 out
    gemm_mfma<false, false, false><<<dim3(48, 4), 256, 0, stream>>>(
        x, Wq, qfull, 256, 3072, 2048, 2048, 3072, 3072, 0, 0, 0);

    // 2) qb[:, :, 0:512] = qnope @ W_UK[h]  (256 x 512 x 128, batched over h)
    gemm_mfma<false, false, true><<<dim3(8, 4, 16), 256, 0, stream>>>(
        qfull, W_UK, qb, 256, 512, 128, 3072, 512, 9216, 192, 65536, 576);

    // 3) qb[:, :, 512:576] = bf16(rope(q_pe))
    pack_qrope<<<512, 256, 0, stream>>>(qfull, pos_q, qb);

    // 4) fused attention, split-K=2 -> partials
    mla_fused_split<<<dim3(256, 2), 256, 0, stream>>>(qb, kvb, topk, Opart, ml);

    // 5) combine partials -> olat (bf16, overlays qb)
    combine_kernel<<<256, 256, 0, stream>>>(Opart, ml, olat);

    // 6) ov_b[t, h*128+v] = olat[t,h,:] . W_UV[h,v,:]  (NT, A bf16, C bf16)
    gemm_mfma<true, true, true><<<dim3(2, 4, 16), 256, 0, stream>>>(
        olat, W_UV, ov_b, 256, 128, 512, 8192, 512, 2048, 512, 65536, 128);

    // 7) out = ov_b @ Wo   (256 x 2048 x 2048), fp32 out
    gemm_mfma<true, false, false><<<dim3(32, 4), 256, 0, stream>>>(
        ov_b, Wo, out, 256, 2048, 2048, 2048, 2048, 2048, 0, 0, 0);
}